// Round 1
// baseline (133.960 us; speedup 1.0000x reference)
//
#include <hip/hip_runtime.h>
#include <hip/hip_bf16.h>

#define N_NODES 4096
#define IN_DIMC 512
#define NHEADS 4
#define DHEAD 64
#define OUT_COLS 256  // NHEADS*DHEAD

typedef __attribute__((ext_vector_type(8))) short short8;
typedef __attribute__((ext_vector_type(4))) float f32x4;

__device__ __forceinline__ short f2bf_rne(float x) {
    unsigned u = __builtin_bit_cast(unsigned, x);
    unsigned r = (u + 0x7fffu + ((u >> 16) & 1u)) >> 16;
    return (short)(r & 0xffffu);
}

// ---------------- Kernel A: h = features @ weights (fp32) ----------------
// grid (64, 4), block 256. Tile 64(M) x 64(N), BK=32, 4x4 per thread.
__global__ __launch_bounds__(256) void k_gemm_h(
    const float* __restrict__ A, const float* __restrict__ W, float* __restrict__ Hm)
{
    __shared__ float As[32][68];  // A^T tile: As[k][m], padded
    __shared__ float Bs[32][68];  // Bs[k][n], padded
    const int m0 = blockIdx.x * 64;
    const int n0 = blockIdx.y * 64;
    const int t = (int)threadIdx.x;
    const int tm = t & 15, tn = t >> 4;
    float acc[4][4] = {};
    for (int k0 = 0; k0 < IN_DIMC; k0 += 32) {
        {
            const int r = t >> 3, kc = (t & 7) << 2;
            float4 v0 = *(const float4*)(A + (size_t)(m0 + r) * IN_DIMC + k0 + kc);
            float4 v1 = *(const float4*)(A + (size_t)(m0 + r + 32) * IN_DIMC + k0 + kc);
            As[kc + 0][r] = v0.x; As[kc + 1][r] = v0.y; As[kc + 2][r] = v0.z; As[kc + 3][r] = v0.w;
            As[kc + 0][r + 32] = v1.x; As[kc + 1][r + 32] = v1.y; As[kc + 2][r + 32] = v1.z; As[kc + 3][r + 32] = v1.w;
            const int rb = t >> 4, nc = (t & 15) << 2;
            float4 w0 = *(const float4*)(W + (size_t)(k0 + rb) * OUT_COLS + n0 + nc);
            float4 w1 = *(const float4*)(W + (size_t)(k0 + rb + 16) * OUT_COLS + n0 + nc);
            *(float4*)&Bs[rb][nc] = w0;
            *(float4*)&Bs[rb + 16][nc] = w1;
        }
        __syncthreads();
        #pragma unroll
        for (int kk = 0; kk < 32; ++kk) {
            const f32x4 a = *(const f32x4*)&As[kk][tm << 2];
            const f32x4 b = *(const f32x4*)&Bs[kk][tn << 2];
            #pragma unroll
            for (int i = 0; i < 4; ++i)
                #pragma unroll
                for (int j = 0; j < 4; ++j)
                    acc[i][j] = fmaf(a[i], b[j], acc[i][j]);
        }
        __syncthreads();
    }
    #pragma unroll
    for (int i = 0; i < 4; ++i) {
        float4 row = make_float4(acc[i][0], acc[i][1], acc[i][2], acc[i][3]);
        *(float4*)(Hm + (size_t)(m0 + (tm << 2) + i) * OUT_COLS + n0 + (tn << 2)) = row;
    }
}

// -------- Kernel B: s1/s2 = h . a1/a2 per head, and hT (bf16 transpose) --------
// grid (64, 4), block 256.
__global__ __launch_bounds__(256) void k_prep(
    const float* __restrict__ Hm, const float* __restrict__ att,
    __hip_bfloat16* __restrict__ hT, float* __restrict__ s1T, float* __restrict__ s2T)
{
    __shared__ float tile[64][65];
    const int m0 = blockIdx.x * 64;
    const int head = blockIdx.y;
    const int t = (int)threadIdx.x;
    #pragma unroll
    for (int it = 0; it < 16; ++it) {
        int idx = it * 256 + t;
        int r = idx >> 6, c = idx & 63;
        tile[r][c] = Hm[(size_t)(m0 + r) * OUT_COLS + head * DHEAD + c];
    }
    __syncthreads();
    {
        const int r = t >> 2, part = t & 3;
        float p1 = 0.f, p2 = 0.f;
        #pragma unroll
        for (int dd = 0; dd < 16; ++dd) {
            int d = part * 16 + dd;
            float v = tile[r][d];
            p1 = fmaf(v, att[head * 128 + d], p1);
            p2 = fmaf(v, att[head * 128 + 64 + d], p2);
        }
        p1 += __shfl_xor(p1, 1); p1 += __shfl_xor(p1, 2);
        p2 += __shfl_xor(p2, 1); p2 += __shfl_xor(p2, 2);
        if (part == 0) {
            s1T[head * N_NODES + m0 + r] = p1;
            s2T[head * N_NODES + m0 + r] = p2;
        }
    }
    #pragma unroll
    for (int it = 0; it < 16; ++it) {
        int idx = it * 256 + t;
        int c = idx >> 6, r = idx & 63;
        hT[(size_t)(head * DHEAD + c) * N_NODES + m0 + r] = __float2bfloat16(tile[r][c]);
    }
}

// ---- Kernel C: fused masked softmax (no max-sub) + PV via bf16 MFMA ----
// grid (256), block 256 = 4 waves (one head each). i-tile = 16, j-chunk = 64.
__global__ __launch_bounds__(256) void k_gat(
    const int* __restrict__ adj, const __hip_bfloat16* __restrict__ hT,
    const float* __restrict__ s1T, const float* __restrict__ s2T,
    const float* __restrict__ bias, float* __restrict__ out)
{
    __shared__ unsigned char adjB[16][72];
    const int i0 = blockIdx.x * 16;
    const int t = (int)threadIdx.x;
    const int head = t >> 6;
    const int lane = t & 63;
    const int il = lane & 15;
    const int q = lane >> 4;
    const float s1v = s1T[head * N_NODES + i0 + il];
    const __hip_bfloat16* hTh = hT + (size_t)(head * DHEAD) * N_NODES;
    const float* s2h = s2T + (size_t)head * N_NODES;
    f32x4 acc0 = {0.f, 0.f, 0.f, 0.f};
    f32x4 acc1 = {0.f, 0.f, 0.f, 0.f};
    f32x4 acc2 = {0.f, 0.f, 0.f, 0.f};
    f32x4 acc3 = {0.f, 0.f, 0.f, 0.f};
    float denom = 0.f;

    for (int j0 = 0; j0 < N_NODES; j0 += 64) {
        __syncthreads();
        {   // cooperative adjacency staging: 16 rows x 64 ints -> bytes in LDS
            const int r = t >> 4, ci = (t & 15) << 2;
            const int4 a4 = *(const int4*)(adj + (size_t)(i0 + r) * N_NODES + j0 + ci);
            unsigned pk = (a4.x ? 1u : 0u) | ((a4.y ? 1u : 0u) << 8) |
                          ((a4.z ? 1u : 0u) << 16) | ((a4.w ? 1u : 0u) << 24);
            *(unsigned*)&adjB[r][ci] = pk;
        }
        __syncthreads();
        #pragma unroll
        for (int sk = 0; sk < 2; ++sk) {
            const int jb = j0 + sk * 32 + q * 8;
            const float4 s2a = *(const float4*)(s2h + jb);
            const float4 s2b = *(const float4*)(s2h + jb + 4);
            const unsigned long long ab =
                *(const unsigned long long*)&adjB[il][sk * 32 + q * 8];
            const float s2arr[8] = {s2a.x, s2a.y, s2a.z, s2a.w,
                                    s2b.x, s2b.y, s2b.z, s2b.w};
            short8 afrag;
            #pragma unroll
            for (int e = 0; e < 8; ++e) {
                float x = s1v + s2arr[e];
                x = fmaxf(x, 0.2f * x);                    // leaky_relu, slope 0.2
                float p = ((ab >> (8 * e)) & 0xffull) ? __expf(x) : 0.f;
                denom += p;
                afrag[e] = f2bf_rne(p);
            }
            const short8 b0 = *(const short8*)(hTh + (size_t)(0 * 16 + il) * N_NODES + jb);
            const short8 b1 = *(const short8*)(hTh + (size_t)(1 * 16 + il) * N_NODES + jb);
            const short8 b2 = *(const short8*)(hTh + (size_t)(2 * 16 + il) * N_NODES + jb);
            const short8 b3 = *(const short8*)(hTh + (size_t)(3 * 16 + il) * N_NODES + jb);
            acc0 = __builtin_amdgcn_mfma_f32_16x16x32_bf16(afrag, b0, acc0, 0, 0, 0);
            acc1 = __builtin_amdgcn_mfma_f32_16x16x32_bf16(afrag, b1, acc1, 0, 0, 0);
            acc2 = __builtin_amdgcn_mfma_f32_16x16x32_bf16(afrag, b2, acc2, 0, 0, 0);
            acc3 = __builtin_amdgcn_mfma_f32_16x16x32_bf16(afrag, b3, acc3, 0, 0, 0);
        }
    }
    // full row-denominator: reduce across the 4 k-groups (lanes sharing il)
    denom += __shfl_xor(denom, 16);
    denom += __shfl_xor(denom, 32);
    #pragma unroll
    for (int r = 0; r < 4; ++r) {
        const int row = q * 4 + r;                 // C/D: row=(lane>>4)*4+reg, col=lane&15
        const float dv = __shfl(denom, row);       // lane 'row' holds denom for i=row
        const float inv = 1.0f / dv;
        const size_t base = (size_t)(i0 + row) * OUT_COLS + head * DHEAD + il;
        out[base + 0]  = acc0[r] * inv + bias[head * DHEAD + 0  + il];
        out[base + 16] = acc1[r] * inv + bias[head * DHEAD + 16 + il];
        out[base + 32] = acc2[r] * inv + bias[head * DHEAD + 32 + il];
        out[base + 48] = acc3[r] * inv + bias[head * DHEAD + 48 + il];
    }
}

extern "C" void kernel_launch(void* const* d_in, const int* in_sizes, int n_in,
                              void* d_out, int out_size, void* d_ws, size_t ws_size,
                              hipStream_t stream) {
    const float* features  = (const float*)d_in[0];
    const int*   adjacency = (const int*)d_in[1];
    const float* weights   = (const float*)d_in[2];
    const float* attention = (const float*)d_in[3];
    const float* bias      = (const float*)d_in[4];
    float* out = (float*)d_out;

    char* ws = (char*)d_ws;
    float*          Hm  = (float*)ws;                                   // 4 MB
    __hip_bfloat16* hT  = (__hip_bfloat16*)(ws + 4u * 1024 * 1024);     // 2 MB
    float*          s1T = (float*)(ws + 6u * 1024 * 1024);              // 64 KB
    float*          s2T = (float*)(ws + 6u * 1024 * 1024 + 64u * 1024); // 64 KB

    k_gemm_h<<<dim3(64, 4), 256, 0, stream>>>(features, weights, Hm);
    k_prep<<<dim3(64, 4), 256, 0, stream>>>(Hm, attention, hT, s1T, s2T);
    k_gat<<<dim3(256), 256, 0, stream>>>(adjacency, hT, s1T, s2T, bias, out);
}

// Round 2
// 123.350 us; speedup vs baseline: 1.0860x; 1.0860x over previous
//
#include <hip/hip_runtime.h>
#include <hip/hip_bf16.h>

#define N_NODES 4096
#define IN_DIMC 512
#define NHEADS 4
#define DHEAD 64
#define OUT_COLS 256  // NHEADS*DHEAD

typedef __attribute__((ext_vector_type(8))) short short8;
typedef __attribute__((ext_vector_type(4))) float f32x4;

// ---------------- Kernel A: h = features @ weights (fp32) ----------------
// grid (64, 4), block 256. Tile 64(M) x 64(N), BK=32, 4x4 per thread.
__global__ __launch_bounds__(256) void k_gemm_h(
    const float* __restrict__ A, const float* __restrict__ W, float* __restrict__ Hm)
{
    __shared__ float As[32][68];  // A^T tile: As[k][m], padded
    __shared__ float Bs[32][68];  // Bs[k][n], padded
    const int m0 = blockIdx.x * 64;
    const int n0 = blockIdx.y * 64;
    const int t = (int)threadIdx.x;
    const int tm = t & 15, tn = t >> 4;
    float acc[4][4] = {};
    for (int k0 = 0; k0 < IN_DIMC; k0 += 32) {
        {
            const int r = t >> 3, kc = (t & 7) << 2;
            float4 v0 = *(const float4*)(A + (size_t)(m0 + r) * IN_DIMC + k0 + kc);
            float4 v1 = *(const float4*)(A + (size_t)(m0 + r + 32) * IN_DIMC + k0 + kc);
            As[kc + 0][r] = v0.x; As[kc + 1][r] = v0.y; As[kc + 2][r] = v0.z; As[kc + 3][r] = v0.w;
            As[kc + 0][r + 32] = v1.x; As[kc + 1][r + 32] = v1.y; As[kc + 2][r + 32] = v1.z; As[kc + 3][r + 32] = v1.w;
            const int rb = t >> 4, nc = (t & 15) << 2;
            float4 w0 = *(const float4*)(W + (size_t)(k0 + rb) * OUT_COLS + n0 + nc);
            float4 w1 = *(const float4*)(W + (size_t)(k0 + rb + 16) * OUT_COLS + n0 + nc);
            *(float4*)&Bs[rb][nc] = w0;
            *(float4*)&Bs[rb + 16][nc] = w1;
        }
        __syncthreads();
        #pragma unroll
        for (int kk = 0; kk < 32; ++kk) {
            const f32x4 a = *(const f32x4*)&As[kk][tm << 2];
            const f32x4 b = *(const f32x4*)&Bs[kk][tn << 2];
            #pragma unroll
            for (int i = 0; i < 4; ++i)
                #pragma unroll
                for (int j = 0; j < 4; ++j)
                    acc[i][j] = fmaf(a[i], b[j], acc[i][j]);
        }
        __syncthreads();
    }
    #pragma unroll
    for (int i = 0; i < 4; ++i) {
        float4 row = make_float4(acc[i][0], acc[i][1], acc[i][2], acc[i][3]);
        *(float4*)(Hm + (size_t)(m0 + (tm << 2) + i) * OUT_COLS + n0 + (tn << 2)) = row;
    }
}

// -------- Kernel B: s1/s2 = h . a1/a2 per head, and hT (bf16 transpose) --------
// grid (64, 4), block 256.
__global__ __launch_bounds__(256) void k_prep(
    const float* __restrict__ Hm, const float* __restrict__ att,
    __hip_bfloat16* __restrict__ hT, float* __restrict__ s1T, float* __restrict__ s2T)
{
    __shared__ float tile[64][65];
    const int m0 = blockIdx.x * 64;
    const int head = blockIdx.y;
    const int t = (int)threadIdx.x;
    #pragma unroll
    for (int it = 0; it < 16; ++it) {
        int idx = it * 256 + t;
        int r = idx >> 6, c = idx & 63;
        tile[r][c] = Hm[(size_t)(m0 + r) * OUT_COLS + head * DHEAD + c];
    }
    __syncthreads();
    {
        const int r = t >> 2, part = t & 3;
        float p1 = 0.f, p2 = 0.f;
        #pragma unroll
        for (int dd = 0; dd < 16; ++dd) {
            int d = part * 16 + dd;
            float v = tile[r][d];
            p1 = fmaf(v, att[head * 128 + d], p1);
            p2 = fmaf(v, att[head * 128 + 64 + d], p2);
        }
        p1 += __shfl_xor(p1, 1); p1 += __shfl_xor(p1, 2);
        p2 += __shfl_xor(p2, 1); p2 += __shfl_xor(p2, 2);
        if (part == 0) {
            s1T[head * N_NODES + m0 + r] = p1;
            s2T[head * N_NODES + m0 + r] = p2;
        }
    }
    #pragma unroll
    for (int it = 0; it < 16; ++it) {
        int idx = it * 256 + t;
        int c = idx >> 6, r = idx & 63;
        hT[(size_t)(head * DHEAD + c) * N_NODES + m0 + r] = __float2bfloat16(tile[r][c]);
    }
}

// ---- Kernel P: adjacency (int32) -> bitmask, one u64 per 64 ints via ballot ----
// word w covers row i = w>>6, cols j = (w&63)*64 + lane; bit 'lane' of word w.
__global__ __launch_bounds__(256) void k_pack(
    const int* __restrict__ adj, unsigned long long* __restrict__ bits)
{
    const int gt = blockIdx.x * 256 + (int)threadIdx.x;
    const int wid = gt >> 6;         // global wave id
    const int lane = gt & 63;
    const int nwaves = (int)gridDim.x * 4;
    const int nwords = (N_NODES * N_NODES) / 64;  // 262144
    for (int w = wid; w < nwords; w += nwaves) {
        const int a = adj[(size_t)w * 64 + lane];
        const unsigned long long m = __ballot(a != 0);
        if (lane == 0) bits[w] = m;
    }
}

// ---- Kernel C: fused masked softmax (no max-sub) + PV via bf16 MFMA ----
// grid (256), block 256 = 4 waves (one head each). i-tile = 16, j-chunk = 64.
// Barrier-free: bitmask adjacency (L2-resident), direct loads, pipelined.
__global__ __launch_bounds__(256) void k_gat(
    const unsigned long long* __restrict__ adjBits, const __hip_bfloat16* __restrict__ hT,
    const float* __restrict__ s1T, const float* __restrict__ s2T,
    const float* __restrict__ bias, float* __restrict__ out)
{
    const int i0 = blockIdx.x * 16;
    const int t = (int)threadIdx.x;
    const int head = t >> 6;
    const int lane = t & 63;
    const int il = lane & 15;
    const int q = lane >> 4;
    const float s1v = s1T[head * N_NODES + i0 + il];
    const __hip_bfloat16* hTh = hT + (size_t)(head * DHEAD) * N_NODES;
    const float* s2h = s2T + (size_t)head * N_NODES;
    const unsigned long long* brow = adjBits + (size_t)(i0 + il) * (N_NODES / 64);
    f32x4 acc0 = {0.f, 0.f, 0.f, 0.f};
    f32x4 acc1 = {0.f, 0.f, 0.f, 0.f};
    f32x4 acc2 = {0.f, 0.f, 0.f, 0.f};
    f32x4 acc3 = {0.f, 0.f, 0.f, 0.f};
    float denom = 0.f;

    #pragma unroll 2
    for (int c = 0; c < N_NODES / 64; ++c) {
        const unsigned long long bits = brow[c];
        const int j0 = c << 6;
        #pragma unroll
        for (int sk = 0; sk < 2; ++sk) {
            const int jb = j0 + (sk << 5) + (q << 3);
            const float4 s2a = *(const float4*)(s2h + jb);
            const float4 s2b = *(const float4*)(s2h + jb + 4);
            const unsigned msk = (unsigned)(bits >> ((sk << 5) + (q << 3))) & 0xffu;
            const float s2arr[8] = {s2a.x, s2a.y, s2a.z, s2a.w,
                                    s2b.x, s2b.y, s2b.z, s2b.w};
            short8 afrag;
            #pragma unroll
            for (int e = 0; e < 8; ++e) {
                float x = s1v + s2arr[e];
                x = fmaxf(x, 0.2f * x);                    // leaky_relu, slope 0.2
                float p = ((msk >> e) & 1u) ? __expf(x) : 0.f;
                denom += p;
                afrag[e] = __builtin_bit_cast(short, __float2bfloat16(p));
            }
            const short8 b0 = *(const short8*)(hTh + (size_t)(0 * 16 + il) * N_NODES + jb);
            const short8 b1 = *(const short8*)(hTh + (size_t)(1 * 16 + il) * N_NODES + jb);
            const short8 b2 = *(const short8*)(hTh + (size_t)(2 * 16 + il) * N_NODES + jb);
            const short8 b3 = *(const short8*)(hTh + (size_t)(3 * 16 + il) * N_NODES + jb);
            acc0 = __builtin_amdgcn_mfma_f32_16x16x32_bf16(afrag, b0, acc0, 0, 0, 0);
            acc1 = __builtin_amdgcn_mfma_f32_16x16x32_bf16(afrag, b1, acc1, 0, 0, 0);
            acc2 = __builtin_amdgcn_mfma_f32_16x16x32_bf16(afrag, b2, acc2, 0, 0, 0);
            acc3 = __builtin_amdgcn_mfma_f32_16x16x32_bf16(afrag, b3, acc3, 0, 0, 0);
        }
    }
    // full row-denominator: reduce across the 4 k-groups (lanes sharing il)
    denom += __shfl_xor(denom, 16);
    denom += __shfl_xor(denom, 32);
    #pragma unroll
    for (int r = 0; r < 4; ++r) {
        const int row = q * 4 + r;                 // C/D: row=(lane>>4)*4+reg, col=lane&15
        const float dv = __shfl(denom, row);       // lane 'row' holds denom for i=row
        const float inv = 1.0f / dv;
        const size_t base = (size_t)(i0 + row) * OUT_COLS + head * DHEAD + il;
        out[base + 0]  = acc0[r] * inv + bias[head * DHEAD + 0  + il];
        out[base + 16] = acc1[r] * inv + bias[head * DHEAD + 16 + il];
        out[base + 32] = acc2[r] * inv + bias[head * DHEAD + 32 + il];
        out[base + 48] = acc3[r] * inv + bias[head * DHEAD + 48 + il];
    }
}

extern "C" void kernel_launch(void* const* d_in, const int* in_sizes, int n_in,
                              void* d_out, int out_size, void* d_ws, size_t ws_size,
                              hipStream_t stream) {
    const float* features  = (const float*)d_in[0];
    const int*   adjacency = (const int*)d_in[1];
    const float* weights   = (const float*)d_in[2];
    const float* attention = (const float*)d_in[3];
    const float* bias      = (const float*)d_in[4];
    float* out = (float*)d_out;

    char* ws = (char*)d_ws;
    float*          Hm  = (float*)ws;                                   // 4 MB
    __hip_bfloat16* hT  = (__hip_bfloat16*)(ws + 4u * 1024 * 1024);     // 2 MB
    float*          s1T = (float*)(ws + 6u * 1024 * 1024);              // 64 KB
    float*          s2T = (float*)(ws + 6u * 1024 * 1024 + 64u * 1024); // 64 KB
    unsigned long long* adjBits =
        (unsigned long long*)(ws + 6u * 1024 * 1024 + 256u * 1024);     // 2 MB

    k_pack<<<dim3(2048), 256, 0, stream>>>(adjacency, adjBits);
    k_gemm_h<<<dim3(64, 4), 256, 0, stream>>>(features, weights, Hm);
    k_prep<<<dim3(64, 4), 256, 0, stream>>>(Hm, attention, hT, s1T, s2T);
    k_gat<<<dim3(256), 256, 0, stream>>>(adjBits, hT, s1T, s2T, bias, out);
}

// Round 3
// 119.261 us; speedup vs baseline: 1.1232x; 1.0343x over previous
//
#include <hip/hip_runtime.h>
#include <hip/hip_bf16.h>

#define N_NODES 4096
#define IN_DIMC 512
#define NHEADS 4
#define DHEAD 64
#define OUT_COLS 256  // NHEADS*DHEAD

typedef __attribute__((ext_vector_type(8))) short short8;
typedef __attribute__((ext_vector_type(4))) float f32x4;

// ---------------- Kernel A: h = features @ weights (fp32) ----------------
// grid (128, 4), block 256. Tile 32(M) x 64(N), BK=32, 4x2 per thread.
// 512 blocks = 2 blocks/CU = 2 waves/SIMD (was 1).
__global__ __launch_bounds__(256) void k_gemm_h(
    const float* __restrict__ A, const float* __restrict__ W, float* __restrict__ Hm)
{
    __shared__ float As[32][36];  // A^T tile: As[k][m], padded
    __shared__ float Bs[32][68];  // Bs[k][n], padded
    const int m0 = blockIdx.x * 32;
    const int n0 = blockIdx.y * 64;
    const int t = (int)threadIdx.x;
    const int tm = t & 7, tn = t >> 3;   // 8 x 32
    float acc[4][2] = {};
    for (int k0 = 0; k0 < IN_DIMC; k0 += 32) {
        {
            const int r = t >> 3, kc = (t & 7) << 2;
            float4 v0 = *(const float4*)(A + (size_t)(m0 + r) * IN_DIMC + k0 + kc);
            As[kc + 0][r] = v0.x; As[kc + 1][r] = v0.y; As[kc + 2][r] = v0.z; As[kc + 3][r] = v0.w;
            const int rb = t >> 4, nc = (t & 15) << 2;
            float4 w0 = *(const float4*)(W + (size_t)(k0 + rb) * OUT_COLS + n0 + nc);
            float4 w1 = *(const float4*)(W + (size_t)(k0 + rb + 16) * OUT_COLS + n0 + nc);
            *(float4*)&Bs[rb][nc] = w0;
            *(float4*)&Bs[rb + 16][nc] = w1;
        }
        __syncthreads();
        #pragma unroll
        for (int kk = 0; kk < 32; ++kk) {
            const f32x4 a = *(const f32x4*)&As[kk][tm << 2];
            const float b0 = Bs[kk][tn * 2], b1 = Bs[kk][tn * 2 + 1];
            #pragma unroll
            for (int i = 0; i < 4; ++i) {
                acc[i][0] = fmaf(a[i], b0, acc[i][0]);
                acc[i][1] = fmaf(a[i], b1, acc[i][1]);
            }
        }
        __syncthreads();
    }
    #pragma unroll
    for (int i = 0; i < 4; ++i) {
        float2 row = make_float2(acc[i][0], acc[i][1]);
        *(float2*)(Hm + (size_t)(m0 + (tm << 2) + i) * OUT_COLS + n0 + tn * 2) = row;
    }
}

// -------- Kernel B: s1/s2 = h . a1/a2 per head, and hT (bf16 transpose) --------
// grid (128, 4), block 256, 32-row tiles.
__global__ __launch_bounds__(256) void k_prep(
    const float* __restrict__ Hm, const float* __restrict__ att,
    __hip_bfloat16* __restrict__ hT, float* __restrict__ s1T, float* __restrict__ s2T)
{
    __shared__ float tile[32][65];
    const int m0 = blockIdx.x * 32;
    const int head = blockIdx.y;
    const int t = (int)threadIdx.x;
    #pragma unroll
    for (int it = 0; it < 8; ++it) {
        int idx = it * 256 + t;
        int r = idx >> 6, c = idx & 63;
        tile[r][c] = Hm[(size_t)(m0 + r) * OUT_COLS + head * DHEAD + c];
    }
    __syncthreads();
    {
        const int r = t >> 3, part = t & 7;   // 32 rows x 8 parts
        float p1 = 0.f, p2 = 0.f;
        #pragma unroll
        for (int dd = 0; dd < 8; ++dd) {
            int d = part * 8 + dd;
            float v = tile[r][d];
            p1 = fmaf(v, att[head * 128 + d], p1);
            p2 = fmaf(v, att[head * 128 + 64 + d], p2);
        }
        p1 += __shfl_xor(p1, 1); p1 += __shfl_xor(p1, 2); p1 += __shfl_xor(p1, 4);
        p2 += __shfl_xor(p2, 1); p2 += __shfl_xor(p2, 2); p2 += __shfl_xor(p2, 4);
        if (part == 0) {
            s1T[head * N_NODES + m0 + r] = p1;
            s2T[head * N_NODES + m0 + r] = p2;
        }
    }
    #pragma unroll
    for (int it = 0; it < 8; ++it) {
        int idx = it * 256 + t;
        int c = idx >> 5, r = idx & 31;
        hT[(size_t)(head * DHEAD + c) * N_NODES + m0 + r] = __float2bfloat16(tile[r][c]);
    }
}

// ---- Kernel P: adjacency (int32) -> bitmask, one u64 per 64 ints via ballot ----
__global__ __launch_bounds__(256) void k_pack(
    const int* __restrict__ adj, unsigned long long* __restrict__ bits)
{
    const int gt = blockIdx.x * 256 + (int)threadIdx.x;
    const int wid = gt >> 6;         // global wave id
    const int lane = gt & 63;
    const int nwaves = (int)gridDim.x * 4;
    const int nwords = (N_NODES * N_NODES) / 64;  // 262144
    #pragma unroll 2
    for (int w = wid; w < nwords; w += nwaves) {
        const int a = adj[(size_t)w * 64 + lane];
        const unsigned long long m = __ballot(a != 0);
        if (lane == 0) bits[w] = m;
    }
}

// ---- Kernel C: fused masked softmax (no max-sub) + PV via bf16 MFMA ----
// grid (256) blocks of 1024 threads = 16 waves = 4 heads x 4 j-segments.
// Each wave: 1/4 of the j range into private accs; LDS cross-seg reduction.
__global__ __launch_bounds__(1024) void k_gat(
    const unsigned long long* __restrict__ adjBits, const __hip_bfloat16* __restrict__ hT,
    const float* __restrict__ s1T, const float* __restrict__ s2T,
    const float* __restrict__ bias, float* __restrict__ out)
{
    __shared__ float accLds[16][1056];   // [wave][row*66 + col]  (66 breaks conflicts)
    __shared__ float denomLds[16][16];
    const int i0 = blockIdx.x * 16;
    const int t = (int)threadIdx.x;
    const int w = t >> 6;
    const int head = w & 3;
    const int seg = w >> 2;              // 0..3
    const int lane = t & 63;
    const int il = lane & 15;
    const int q = lane >> 4;
    const float s1v = s1T[head * N_NODES + i0 + il];
    const __hip_bfloat16* hTh = hT + (size_t)(head * DHEAD) * N_NODES;
    const float* s2h = s2T + (size_t)head * N_NODES;
    const unsigned long long* brow = adjBits + (size_t)(i0 + il) * (N_NODES / 64);
    f32x4 acc0 = {0.f, 0.f, 0.f, 0.f};
    f32x4 acc1 = {0.f, 0.f, 0.f, 0.f};
    f32x4 acc2 = {0.f, 0.f, 0.f, 0.f};
    f32x4 acc3 = {0.f, 0.f, 0.f, 0.f};
    float denom = 0.f;

    const int cBeg = seg * 16;           // 16 chunks of 64 j per segment
    #pragma unroll 2
    for (int c = cBeg; c < cBeg + 16; ++c) {
        const unsigned long long bits = brow[c];
        const int j0 = c << 6;
        #pragma unroll
        for (int sk = 0; sk < 2; ++sk) {
            const int jb = j0 + (sk << 5) + (q << 3);
            const float4 s2a = *(const float4*)(s2h + jb);
            const float4 s2b = *(const float4*)(s2h + jb + 4);
            const unsigned msk = (unsigned)(bits >> ((sk << 5) + (q << 3))) & 0xffu;
            const float s2arr[8] = {s2a.x, s2a.y, s2a.z, s2a.w,
                                    s2b.x, s2b.y, s2b.z, s2b.w};
            short8 afrag;
            #pragma unroll
            for (int e = 0; e < 8; ++e) {
                float x = s1v + s2arr[e];
                x = fmaxf(x, 0.2f * x);                    // leaky_relu, slope 0.2
                float p = ((msk >> e) & 1u) ? __expf(x) : 0.f;
                denom += p;
                afrag[e] = __builtin_bit_cast(short, __float2bfloat16(p));
            }
            const short8 b0 = *(const short8*)(hTh + (size_t)(0 * 16 + il) * N_NODES + jb);
            const short8 b1 = *(const short8*)(hTh + (size_t)(1 * 16 + il) * N_NODES + jb);
            const short8 b2 = *(const short8*)(hTh + (size_t)(2 * 16 + il) * N_NODES + jb);
            const short8 b3 = *(const short8*)(hTh + (size_t)(3 * 16 + il) * N_NODES + jb);
            acc0 = __builtin_amdgcn_mfma_f32_16x16x32_bf16(afrag, b0, acc0, 0, 0, 0);
            acc1 = __builtin_amdgcn_mfma_f32_16x16x32_bf16(afrag, b1, acc1, 0, 0, 0);
            acc2 = __builtin_amdgcn_mfma_f32_16x16x32_bf16(afrag, b2, acc2, 0, 0, 0);
            acc3 = __builtin_amdgcn_mfma_f32_16x16x32_bf16(afrag, b3, acc3, 0, 0, 0);
        }
    }
    // intra-wave: full row-denominator for this segment
    denom += __shfl_xor(denom, 16);
    denom += __shfl_xor(denom, 32);
    // publish partials
    #pragma unroll
    for (int r = 0; r < 4; ++r) {
        const int row = q * 4 + r;       // C/D: row=(lane>>4)*4+reg, col=lane&15
        accLds[w][row * 66 + 0  + il] = acc0[r];
        accLds[w][row * 66 + 16 + il] = acc1[r];
        accLds[w][row * 66 + 32 + il] = acc2[r];
        accLds[w][row * 66 + 48 + il] = acc3[r];
    }
    if (q == 0) denomLds[w][il] = denom;
    __syncthreads();
    // cross-segment reduction + epilogue: waves 0..3 (seg 0), head = w
    if (w < 4) {
        #pragma unroll
        for (int r = 0; r < 4; ++r) {
            const int row = q * 4 + r;
            const float dsum = denomLds[w][row] + denomLds[w + 4][row]
                             + denomLds[w + 8][row] + denomLds[w + 12][row];
            const float inv = 1.0f / dsum;
            #pragma unroll
            for (int k = 0; k < 4; ++k) {
                const int cidx = row * 66 + k * 16 + il;
                const float v = accLds[w][cidx] + accLds[w + 4][cidx]
                              + accLds[w + 8][cidx] + accLds[w + 12][cidx];
                out[(size_t)(i0 + row) * OUT_COLS + w * DHEAD + k * 16 + il] =
                    v * inv + bias[w * DHEAD + k * 16 + il];
            }
        }
    }
}

extern "C" void kernel_launch(void* const* d_in, const int* in_sizes, int n_in,
                              void* d_out, int out_size, void* d_ws, size_t ws_size,
                              hipStream_t stream) {
    const float* features  = (const float*)d_in[0];
    const int*   adjacency = (const int*)d_in[1];
    const float* weights   = (const float*)d_in[2];
    const float* attention = (const float*)d_in[3];
    const float* bias      = (const float*)d_in[4];
    float* out = (float*)d_out;

    char* ws = (char*)d_ws;
    float*          Hm  = (float*)ws;                                   // 4 MB
    __hip_bfloat16* hT  = (__hip_bfloat16*)(ws + 4u * 1024 * 1024);     // 2 MB
    float*          s1T = (float*)(ws + 6u * 1024 * 1024);              // 64 KB
    float*          s2T = (float*)(ws + 6u * 1024 * 1024 + 64u * 1024); // 64 KB
    unsigned long long* adjBits =
        (unsigned long long*)(ws + 6u * 1024 * 1024 + 256u * 1024);     // 2 MB

    k_pack<<<dim3(2048), 256, 0, stream>>>(adjacency, adjBits);
    k_gemm_h<<<dim3(128, 4), 256, 0, stream>>>(features, weights, Hm);
    k_prep<<<dim3(128, 4), 256, 0, stream>>>(Hm, attention, hT, s1T, s2T);
    k_gat<<<dim3(256), 1024, 0, stream>>>(adjBits, hT, s1T, s2T, bias, out);
}

// Round 4
// 108.085 us; speedup vs baseline: 1.2394x; 1.1034x over previous
//
#include <hip/hip_runtime.h>
#include <hip/hip_bf16.h>

#define N_NODES 4096
#define IN_DIMC 512
#define NHEADS 4
#define DHEAD 64
#define OUT_COLS 256  // NHEADS*DHEAD

typedef __attribute__((ext_vector_type(8))) short short8;
typedef __attribute__((ext_vector_type(4))) float f32x4;

__device__ __forceinline__ short bf16b(float x) {
    return __builtin_bit_cast(short, __float2bfloat16(x));
}

// ---- Kernel A (fused): h = features @ weights, then s1/s2 + hT epilogue ----
// grid (128, 4), block 256. Tile 32(M) x 64(N)=one head, BK=32, 4x2 per thread.
__global__ __launch_bounds__(256) void k_gemm_fused(
    const float* __restrict__ A, const float* __restrict__ W,
    const float* __restrict__ att,
    __hip_bfloat16* __restrict__ hT, float* __restrict__ s1T, float* __restrict__ s2T)
{
    __shared__ float As[32][36];   // A^T tile: As[k][m], padded
    __shared__ float Bs[32][68];   // Bs[k][n], padded
    __shared__ float ht[64][33];   // h tile transposed: ht[c][r], padded
    const int m0 = blockIdx.x * 32;
    const int head = blockIdx.y;
    const int n0 = head * 64;
    const int t = (int)threadIdx.x;
    const int tm = t & 7, tn = t >> 3;   // 8 x 32
    float acc[4][2] = {};
    for (int k0 = 0; k0 < IN_DIMC; k0 += 32) {
        {
            const int r = t >> 3, kc = (t & 7) << 2;
            float4 v0 = *(const float4*)(A + (size_t)(m0 + r) * IN_DIMC + k0 + kc);
            As[kc + 0][r] = v0.x; As[kc + 1][r] = v0.y; As[kc + 2][r] = v0.z; As[kc + 3][r] = v0.w;
            const int rb = t >> 4, nc = (t & 15) << 2;
            float4 w0 = *(const float4*)(W + (size_t)(k0 + rb) * OUT_COLS + n0 + nc);
            float4 w1 = *(const float4*)(W + (size_t)(k0 + rb + 16) * OUT_COLS + n0 + nc);
            *(float4*)&Bs[rb][nc] = w0;
            *(float4*)&Bs[rb + 16][nc] = w1;
        }
        __syncthreads();
        #pragma unroll
        for (int kk = 0; kk < 32; ++kk) {
            const f32x4 a = *(const f32x4*)&As[kk][tm << 2];
            const float b0 = Bs[kk][tn * 2], b1 = Bs[kk][tn * 2 + 1];
            #pragma unroll
            for (int i = 0; i < 4; ++i) {
                acc[i][0] = fmaf(a[i], b0, acc[i][0]);
                acc[i][1] = fmaf(a[i], b1, acc[i][1]);
            }
        }
        __syncthreads();
    }
    // stage h tile (f32) transposed in LDS: ht[c][r]
    #pragma unroll
    for (int i = 0; i < 4; ++i) {
        ht[tn * 2 + 0][(tm << 2) + i] = acc[i][0];
        ht[tn * 2 + 1][(tm << 2) + i] = acc[i][1];
    }
    __syncthreads();
    // hT write: bf16, coalesced short8 per thread
    {
        const int c = t >> 2, rb = (t & 3) << 3;
        short8 hv;
        #pragma unroll
        for (int k = 0; k < 8; ++k) hv[k] = bf16b(ht[c][rb + k]);
        *(short8*)(hT + (size_t)(head * DHEAD + c) * N_NODES + m0 + rb) = hv;
    }
    // s1/s2: row r = t>>3 (32 rows), part = t&7 covers 8 cols
    {
        const int r = t >> 3, part = t & 7;
        float p1 = 0.f, p2 = 0.f;
        #pragma unroll
        for (int dd = 0; dd < 8; ++dd) {
            const int d = part * 8 + dd;
            const float v = ht[d][r];
            p1 = fmaf(v, att[head * 128 + d], p1);
            p2 = fmaf(v, att[head * 128 + 64 + d], p2);
        }
        p1 += __shfl_xor(p1, 1); p1 += __shfl_xor(p1, 2); p1 += __shfl_xor(p1, 4);
        p2 += __shfl_xor(p2, 1); p2 += __shfl_xor(p2, 2); p2 += __shfl_xor(p2, 4);
        if (part == 0) {
            s1T[head * N_NODES + m0 + r] = p1;
            s2T[head * N_NODES + m0 + r] = p2;
        }
    }
}

// ---- Kernel P: adjacency (int32) -> bitmask, 4 words per wave-iter (ILP 4) ----
__global__ __launch_bounds__(256) void k_pack(
    const int* __restrict__ adj, unsigned long long* __restrict__ bits)
{
    const int gt = blockIdx.x * 256 + (int)threadIdx.x;
    const int wv = gt >> 6;
    const int lane = gt & 63;
    const int nwaves = (int)gridDim.x * 4;
    const int nwords = (N_NODES * N_NODES) / 64;  // 262144
    for (int w = wv * 4; w < nwords; w += nwaves * 4) {
        const int a0 = adj[(size_t)(w + 0) * 64 + lane];
        const int a1 = adj[(size_t)(w + 1) * 64 + lane];
        const int a2 = adj[(size_t)(w + 2) * 64 + lane];
        const int a3 = adj[(size_t)(w + 3) * 64 + lane];
        const unsigned long long m0 = __ballot(a0 != 0);
        const unsigned long long m1 = __ballot(a1 != 0);
        const unsigned long long m2 = __ballot(a2 != 0);
        const unsigned long long m3 = __ballot(a3 != 0);
        if (lane == 0) {
            bits[w + 0] = m0; bits[w + 1] = m1;
            bits[w + 2] = m2; bits[w + 3] = m3;
        }
    }
}

// ---- Kernel C: fused masked softmax + PV via bf16 MFMA, software-pipelined ----
// grid (256) blocks of 1024 threads = 16 waves = 4 heads x 4 j-segments.
// Each wave: 1/4 of j range, 32 steps of 32 j; explicit 1-step load prefetch.
__global__ __launch_bounds__(1024, 4) void k_gat(
    const unsigned long long* __restrict__ adjBits, const __hip_bfloat16* __restrict__ hT,
    const float* __restrict__ s1T, const float* __restrict__ s2T,
    const float* __restrict__ bias, float* __restrict__ out)
{
    __shared__ float accLds[16][1056];   // [wave][row*66 + col]
    __shared__ float denomLds[16][16];
    const int i0 = blockIdx.x * 16;
    const int t = (int)threadIdx.x;
    const int w = t >> 6;
    const int head = w & 3;
    const int seg = w >> 2;              // 0..3
    const int lane = t & 63;
    const int il = lane & 15;
    const int q = lane >> 4;
    const float s1v = s1T[head * N_NODES + i0 + il];
    const __hip_bfloat16* hTh = hT + (size_t)(head * DHEAD) * N_NODES;
    const float* s2h = s2T + (size_t)head * N_NODES;
    const unsigned long long* brow = adjBits + (size_t)(i0 + il) * (N_NODES / 64);
    f32x4 acc0 = {0.f, 0.f, 0.f, 0.f};
    f32x4 acc1 = {0.f, 0.f, 0.f, 0.f};
    f32x4 acc2 = {0.f, 0.f, 0.f, 0.f};
    f32x4 acc3 = {0.f, 0.f, 0.f, 0.f};
    float denom = 0.f;

    const int cBeg = seg * 16;           // 16 chunks of 64 j; 32 steps of 32 j
    // prologue: load step 0
    unsigned long long bitsCur = brow[cBeg];
    {
        const int jb0 = (cBeg << 6) + (q << 3);
        float4 sA = *(const float4*)(s2h + jb0);
        float4 sB = *(const float4*)(s2h + jb0 + 4);
        short8 hb0 = *(const short8*)(hTh + (size_t)(0 * 16 + il) * N_NODES + jb0);
        short8 hb1 = *(const short8*)(hTh + (size_t)(1 * 16 + il) * N_NODES + jb0);
        short8 hb2 = *(const short8*)(hTh + (size_t)(2 * 16 + il) * N_NODES + jb0);
        short8 hb3 = *(const short8*)(hTh + (size_t)(3 * 16 + il) * N_NODES + jb0);

        #pragma unroll 2
        for (int s = 0; s < 32; ++s) {
            // ---- issue next-step loads first (counted-vmcnt overlap) ----
            const int sn = (s < 31) ? s + 1 : 31;
            const int cn = cBeg + (sn >> 1);
            const int jn = (cn << 6) + ((sn & 1) << 5) + (q << 3);
            unsigned long long bitsNxt = bitsCur;
            if ((sn & 1) == 0) bitsNxt = brow[cn];
            const float4 nA = *(const float4*)(s2h + jn);
            const float4 nB = *(const float4*)(s2h + jn + 4);
            const short8 nb0 = *(const short8*)(hTh + (size_t)(0 * 16 + il) * N_NODES + jn);
            const short8 nb1 = *(const short8*)(hTh + (size_t)(1 * 16 + il) * N_NODES + jn);
            const short8 nb2 = *(const short8*)(hTh + (size_t)(2 * 16 + il) * N_NODES + jn);
            const short8 nb3 = *(const short8*)(hTh + (size_t)(3 * 16 + il) * N_NODES + jn);
            // ---- compute current step ----
            const int sk = s & 1;
            const unsigned msk = (unsigned)(bitsCur >> ((sk << 5) + (q << 3))) & 0xffu;
            short8 afrag;
            {
                float x, p;
                x = s1v + sA.x; x = fmaxf(x, 0.2f * x);
                p = (msk & 1u)   ? __expf(x) : 0.f; denom += p; afrag[0] = bf16b(p);
                x = s1v + sA.y; x = fmaxf(x, 0.2f * x);
                p = (msk & 2u)   ? __expf(x) : 0.f; denom += p; afrag[1] = bf16b(p);
                x = s1v + sA.z; x = fmaxf(x, 0.2f * x);
                p = (msk & 4u)   ? __expf(x) : 0.f; denom += p; afrag[2] = bf16b(p);
                x = s1v + sA.w; x = fmaxf(x, 0.2f * x);
                p = (msk & 8u)   ? __expf(x) : 0.f; denom += p; afrag[3] = bf16b(p);
                x = s1v + sB.x; x = fmaxf(x, 0.2f * x);
                p = (msk & 16u)  ? __expf(x) : 0.f; denom += p; afrag[4] = bf16b(p);
                x = s1v + sB.y; x = fmaxf(x, 0.2f * x);
                p = (msk & 32u)  ? __expf(x) : 0.f; denom += p; afrag[5] = bf16b(p);
                x = s1v + sB.z; x = fmaxf(x, 0.2f * x);
                p = (msk & 64u)  ? __expf(x) : 0.f; denom += p; afrag[6] = bf16b(p);
                x = s1v + sB.w; x = fmaxf(x, 0.2f * x);
                p = (msk & 128u) ? __expf(x) : 0.f; denom += p; afrag[7] = bf16b(p);
            }
            acc0 = __builtin_amdgcn_mfma_f32_16x16x32_bf16(afrag, hb0, acc0, 0, 0, 0);
            acc1 = __builtin_amdgcn_mfma_f32_16x16x32_bf16(afrag, hb1, acc1, 0, 0, 0);
            acc2 = __builtin_amdgcn_mfma_f32_16x16x32_bf16(afrag, hb2, acc2, 0, 0, 0);
            acc3 = __builtin_amdgcn_mfma_f32_16x16x32_bf16(afrag, hb3, acc3, 0, 0, 0);
            // ---- rotate ----
            bitsCur = bitsNxt;
            sA = nA; sB = nB;
            hb0 = nb0; hb1 = nb1; hb2 = nb2; hb3 = nb3;
        }
    }
    // intra-wave: full row-denominator for this segment
    denom += __shfl_xor(denom, 16);
    denom += __shfl_xor(denom, 32);
    // publish partials
    #pragma unroll
    for (int r = 0; r < 4; ++r) {
        const int row = q * 4 + r;       // C/D: row=(lane>>4)*4+reg, col=lane&15
        accLds[w][row * 66 + 0  + il] = acc0[r];
        accLds[w][row * 66 + 16 + il] = acc1[r];
        accLds[w][row * 66 + 32 + il] = acc2[r];
        accLds[w][row * 66 + 48 + il] = acc3[r];
    }
    if (q == 0) denomLds[w][il] = denom;
    __syncthreads();
    // cross-segment reduction + epilogue: waves 0..3, head = w
    if (w < 4) {
        #pragma unroll
        for (int r = 0; r < 4; ++r) {
            const int row = q * 4 + r;
            const float dsum = denomLds[w][row] + denomLds[w + 4][row]
                             + denomLds[w + 8][row] + denomLds[w + 12][row];
            const float inv = 1.0f / dsum;
            #pragma unroll
            for (int k = 0; k < 4; ++k) {
                const int cidx = row * 66 + k * 16 + il;
                const float v = accLds[w][cidx] + accLds[w + 4][cidx]
                              + accLds[w + 8][cidx] + accLds[w + 12][cidx];
                out[(size_t)(i0 + row) * OUT_COLS + w * DHEAD + k * 16 + il] =
                    v * inv + bias[w * DHEAD + k * 16 + il];
            }
        }
    }
}

extern "C" void kernel_launch(void* const* d_in, const int* in_sizes, int n_in,
                              void* d_out, int out_size, void* d_ws, size_t ws_size,
                              hipStream_t stream) {
    const float* features  = (const float*)d_in[0];
    const int*   adjacency = (const int*)d_in[1];
    const float* weights   = (const float*)d_in[2];
    const float* attention = (const float*)d_in[3];
    const float* bias      = (const float*)d_in[4];
    float* out = (float*)d_out;

    char* ws = (char*)d_ws;
    __hip_bfloat16* hT  = (__hip_bfloat16*)ws;                          // 2 MB
    float*          s1T = (float*)(ws + 2u * 1024 * 1024);              // 64 KB
    float*          s2T = (float*)(ws + 2u * 1024 * 1024 + 64u * 1024); // 64 KB
    unsigned long long* adjBits =
        (unsigned long long*)(ws + 2u * 1024 * 1024 + 128u * 1024);     // 2 MB

    k_pack<<<dim3(2048), 256, 0, stream>>>(adjacency, adjBits);
    k_gemm_fused<<<dim3(128, 4), 256, 0, stream>>>(features, weights, attention,
                                                   hT, s1T, s2T);
    k_gat<<<dim3(256), 1024, 0, stream>>>(adjBits, hT, s1T, s2T, bias, out);
}

// Round 5
// 72.221 us; speedup vs baseline: 1.8549x; 1.4966x over previous
//
#include <hip/hip_runtime.h>
#include <hip/hip_bf16.h>

#define N_NODES 4096
#define IN_DIMC 512
#define NHEADS 4
#define DHEAD 64
#define OUT_COLS 256  // NHEADS*DHEAD
#define HP_HEAD_BYTES (N_NODES * DHEAD * 2)  // 512 KB per head

typedef __attribute__((ext_vector_type(8))) short short8;
typedef __attribute__((ext_vector_type(4))) float f32x4;

__device__ __forceinline__ short bf16b(float x) {
    return __builtin_bit_cast(short, __float2bfloat16(x));
}

__device__ __forceinline__ void gload_lds16(const void* g, void* l) {
    __builtin_amdgcn_global_load_lds((const __attribute__((address_space(1))) void*)g,
                                     (__attribute__((address_space(3))) void*)l,
                                     16, 0, 0);
}

// ---- Kernel A (fused): h = features @ weights, then s1/s2 + packed-hP epilogue ----
// grid (128, 4), block 256. Tile 32(M=nodes j) x 64(N=d)=one head, BK=32.
// hP layout (per head): element (d, j) -> 16B-slot ((g*4 + d/16)*64 + q*16 + d%16),
// elem j%8 inside; g = j/32, q = (j%32)/8.  (= MFMA B-frag order, lane-linear)
__global__ __launch_bounds__(256) void k_gemm_fused(
    const float* __restrict__ A, const float* __restrict__ W,
    const float* __restrict__ att,
    char* __restrict__ hP, float* __restrict__ s1T, float* __restrict__ s2T)
{
    __shared__ float As[32][36];   // A^T tile: As[k][m], padded
    __shared__ float Bs[32][68];   // Bs[k][n], padded
    __shared__ float ht[64][33];   // h tile transposed: ht[d][node], padded
    const int m0 = blockIdx.x * 32;
    const int head = blockIdx.y;
    const int n0 = head * 64;
    const int t = (int)threadIdx.x;
    const int tm = t & 7, tn = t >> 3;   // 8 x 32
    float acc[4][2] = {};
    for (int k0 = 0; k0 < IN_DIMC; k0 += 32) {
        {
            const int r = t >> 3, kc = (t & 7) << 2;
            float4 v0 = *(const float4*)(A + (size_t)(m0 + r) * IN_DIMC + k0 + kc);
            As[kc + 0][r] = v0.x; As[kc + 1][r] = v0.y; As[kc + 2][r] = v0.z; As[kc + 3][r] = v0.w;
            const int rb = t >> 4, nc = (t & 15) << 2;
            float4 w0 = *(const float4*)(W + (size_t)(k0 + rb) * OUT_COLS + n0 + nc);
            float4 w1 = *(const float4*)(W + (size_t)(k0 + rb + 16) * OUT_COLS + n0 + nc);
            *(float4*)&Bs[rb][nc] = w0;
            *(float4*)&Bs[rb + 16][nc] = w1;
        }
        __syncthreads();
        #pragma unroll
        for (int kk = 0; kk < 32; ++kk) {
            const f32x4 a = *(const f32x4*)&As[kk][tm << 2];
            const float b0 = Bs[kk][tn * 2], b1 = Bs[kk][tn * 2 + 1];
            #pragma unroll
            for (int i = 0; i < 4; ++i) {
                acc[i][0] = fmaf(a[i], b0, acc[i][0]);
                acc[i][1] = fmaf(a[i], b1, acc[i][1]);
            }
        }
        __syncthreads();
    }
    // stage h tile (f32) in LDS: ht[d][node]
    #pragma unroll
    for (int i = 0; i < 4; ++i) {
        ht[tn * 2 + 0][(tm << 2) + i] = acc[i][0];
        ht[tn * 2 + 1][(tm << 2) + i] = acc[i][1];
    }
    __syncthreads();
    // packed hP write: thread t -> d = t>>2, qq = t&3: 8 consecutive j at m0+qq*8
    {
        const int d = t >> 2, qq = t & 3;
        short8 hv;
        #pragma unroll
        for (int k = 0; k < 8; ++k) hv[k] = bf16b(ht[d][qq * 8 + k]);
        const size_t off16 = ((size_t)(m0 >> 5) * 4 + (d >> 4)) * 64 + qq * 16 + (d & 15);
        *(short8*)(hP + (size_t)head * HP_HEAD_BYTES + off16 * 16) = hv;
    }
    // s1/s2: row r = t>>3 (32 nodes), part = t&7 covers 8 d
    {
        const int r = t >> 3, part = t & 7;
        float p1 = 0.f, p2 = 0.f;
        #pragma unroll
        for (int dd = 0; dd < 8; ++dd) {
            const int d = part * 8 + dd;
            const float v = ht[d][r];
            p1 = fmaf(v, att[head * 128 + d], p1);
            p2 = fmaf(v, att[head * 128 + 64 + d], p2);
        }
        p1 += __shfl_xor(p1, 1); p1 += __shfl_xor(p1, 2); p1 += __shfl_xor(p1, 4);
        p2 += __shfl_xor(p2, 1); p2 += __shfl_xor(p2, 2); p2 += __shfl_xor(p2, 4);
        if (part == 0) {
            s1T[head * N_NODES + m0 + r] = p1;
            s2T[head * N_NODES + m0 + r] = p2;
        }
    }
}

// ---- Kernel P: adjacency -> TRANSPOSED bitmask bitsT[c][i], c = j/64 ----
// Wave n: row i = n>>6, col-chunk c = n&63 -> 64 consecutive waves stream one row.
__global__ __launch_bounds__(256) void k_pack(
    const int* __restrict__ adj, unsigned long long* __restrict__ bitsT)
{
    const int gt = blockIdx.x * 256 + (int)threadIdx.x;
    const int wv = gt >> 6;
    const int lane = gt & 63;
    const int nwaves = (int)gridDim.x * 4;
    const int nwords = (N_NODES * N_NODES) / 64;  // 262144
    for (int n = wv * 4; n < nwords; n += nwaves * 4) {
        const int i0 = (n + 0) >> 6, c0 = (n + 0) & 63;
        const int i1 = (n + 1) >> 6, c1 = (n + 1) & 63;
        const int i2 = (n + 2) >> 6, c2 = (n + 2) & 63;
        const int i3 = (n + 3) >> 6, c3 = (n + 3) & 63;
        const int a0 = adj[(size_t)i0 * N_NODES + c0 * 64 + lane];
        const int a1 = adj[(size_t)i1 * N_NODES + c1 * 64 + lane];
        const int a2 = adj[(size_t)i2 * N_NODES + c2 * 64 + lane];
        const int a3 = adj[(size_t)i3 * N_NODES + c3 * 64 + lane];
        const unsigned long long m0 = __ballot(a0 != 0);
        const unsigned long long m1 = __ballot(a1 != 0);
        const unsigned long long m2 = __ballot(a2 != 0);
        const unsigned long long m3 = __ballot(a3 != 0);
        if (lane == 0) {
            bitsT[(size_t)c0 * N_NODES + i0] = m0;
            bitsT[(size_t)c1 * N_NODES + i1] = m1;
            bitsT[(size_t)c2 * N_NODES + i2] = m2;
            bitsT[(size_t)c3 * N_NODES + i3] = m3;
        }
    }
}

// ---- Kernel C: fused masked softmax + PV, global_load_lds double-buffer ----
// grid (256) blocks of 1024 = 16 waves = 4 heads x 4 j-segments.
// Per-wave PRIVATE 2x4KB LDS staging (no barriers in loop), vmcnt-counted.
__global__ __launch_bounds__(1024, 4) void k_gat(
    const unsigned long long* __restrict__ bitsT, const char* __restrict__ hP,
    const float* __restrict__ s1T, const float* __restrict__ s2T,
    const float* __restrict__ bias, float* __restrict__ out)
{
    __shared__ __align__(16) char stage[16 * 8192];   // 128 KB: 16 waves x 2 bufs x 4KB
    const int i0 = blockIdx.x * 16;
    const int t = (int)threadIdx.x;
    const int w = t >> 6;
    const int head = w & 3;
    const int seg = w >> 2;              // 0..3
    const int lane = t & 63;
    const int il = lane & 15;
    const int q = lane >> 4;
    char* myStage = stage + w * 8192;
    const char* hPh = hP + (size_t)head * HP_HEAD_BYTES;
    const float* s2h = s2T + head * N_NODES;
    const float s1v = s1T[head * N_NODES + i0 + il];
    f32x4 acc[4] = {{0.f,0.f,0.f,0.f},{0.f,0.f,0.f,0.f},{0.f,0.f,0.f,0.f},{0.f,0.f,0.f,0.f}};
    float denom = 0.f;

    const int g0 = seg * 32;             // 32 steps of 32 j each
    // prologue batch (step 0): bits + s2 + 4x global_load_lds
    unsigned long long bitsCur = bitsT[(size_t)(g0 >> 1) * N_NODES + i0 + il];
    float4 sAc = *(const float4*)(s2h + g0 * 32 + q * 8);
    float4 sBc = *(const float4*)(s2h + g0 * 32 + q * 8 + 4);
    #pragma unroll
    for (int dblk = 0; dblk < 4; ++dblk)
        gload_lds16(hPh + (size_t)g0 * 4096 + dblk * 1024 + lane * 16,
                    myStage + dblk * 1024);

    #pragma unroll 2
    for (int s = 0; s < 32; ++s) {
        const int g = g0 + s;
        unsigned long long bitsNxt = bitsCur;
        float4 sAn = sAc, sBn = sBc;
        if (s < 31) {
            const int gn = g + 1;
            bitsNxt = bitsT[(size_t)(gn >> 1) * N_NODES + i0 + il];
            sAn = *(const float4*)(s2h + gn * 32 + q * 8);
            sBn = *(const float4*)(s2h + gn * 32 + q * 8 + 4);
            char* ldst = myStage + ((s + 1) & 1) * 4096;
            #pragma unroll
            for (int dblk = 0; dblk < 4; ++dblk)
                gload_lds16(hPh + (size_t)gn * 4096 + dblk * 1024 + lane * 16,
                            ldst + dblk * 1024);
            // previous batch (7 ops) drained; this batch (7) stays in flight
            asm volatile("s_waitcnt vmcnt(7)" ::: "memory");
        } else {
            asm volatile("s_waitcnt vmcnt(0)" ::: "memory");
        }
        // ---- P-gen for current step (32 j) ----
        const unsigned msk = (unsigned)(bitsCur >> ((g & 1) * 32 + q * 8)) & 0xffu;
        short8 afrag;
        {
            float x, p;
            x = s1v + sAc.x; x = fmaxf(x, 0.2f * x);
            p = (msk & 1u)   ? __expf(x) : 0.f; denom += p; afrag[0] = bf16b(p);
            x = s1v + sAc.y; x = fmaxf(x, 0.2f * x);
            p = (msk & 2u)   ? __expf(x) : 0.f; denom += p; afrag[1] = bf16b(p);
            x = s1v + sAc.z; x = fmaxf(x, 0.2f * x);
            p = (msk & 4u)   ? __expf(x) : 0.f; denom += p; afrag[2] = bf16b(p);
            x = s1v + sAc.w; x = fmaxf(x, 0.2f * x);
            p = (msk & 8u)   ? __expf(x) : 0.f; denom += p; afrag[3] = bf16b(p);
            x = s1v + sBc.x; x = fmaxf(x, 0.2f * x);
            p = (msk & 16u)  ? __expf(x) : 0.f; denom += p; afrag[4] = bf16b(p);
            x = s1v + sBc.y; x = fmaxf(x, 0.2f * x);
            p = (msk & 32u)  ? __expf(x) : 0.f; denom += p; afrag[5] = bf16b(p);
            x = s1v + sBc.z; x = fmaxf(x, 0.2f * x);
            p = (msk & 64u)  ? __expf(x) : 0.f; denom += p; afrag[6] = bf16b(p);
            x = s1v + sBc.w; x = fmaxf(x, 0.2f * x);
            p = (msk & 128u) ? __expf(x) : 0.f; denom += p; afrag[7] = bf16b(p);
        }
        // ---- lane-linear conflict-free ds_read + MFMA ----
        const short8* fb = (const short8*)(myStage + (s & 1) * 4096);
        #pragma unroll
        for (int dblk = 0; dblk < 4; ++dblk) {
            const short8 b = fb[dblk * 64 + lane];
            acc[dblk] = __builtin_amdgcn_mfma_f32_16x16x32_bf16(afrag, b, acc[dblk], 0, 0, 0);
        }
        bitsCur = bitsNxt; sAc = sAn; sBc = sBn;
    }
    // intra-wave row-denominator for this segment
    denom += __shfl_xor(denom, 16);
    denom += __shfl_xor(denom, 32);

    __syncthreads();                     // all loops done; repurpose stage for reduction
    float* red  = (float*)stage;                 // 12 waves x 1024 f32 partials (48 KB)
    float* dred = (float*)(stage + 49152);       // 12 waves x 16 f32 denoms
    if (seg > 0) {
        const int p = (w - 4) * 1024;
        #pragma unroll
        for (int r = 0; r < 4; ++r) {
            const int row = q * 4 + r;           // C/D: row=(lane>>4)*4+reg, col=lane&15
            red[p + row * 64 + 0  + il] = acc[0][r];
            red[p + row * 64 + 16 + il] = acc[1][r];
            red[p + row * 64 + 32 + il] = acc[2][r];
            red[p + row * 64 + 48 + il] = acc[3][r];
        }
        if (q == 0) dred[(w - 4) * 16 + il] = denom;
    }
    __syncthreads();
    if (seg == 0) {                      // w == head
        #pragma unroll
        for (int r = 0; r < 4; ++r) {
            const int row = q * 4 + r;
            float dsum = __shfl(denom, row);
            #pragma unroll
            for (int s = 1; s < 4; ++s)
                dsum += dred[((s - 1) * 4 + w) * 16 + row];
            const float inv = 1.0f / dsum;
            #pragma unroll
            for (int dblk = 0; dblk < 4; ++dblk) {
                float v = acc[dblk][r];
                #pragma unroll
                for (int s = 1; s < 4; ++s)
                    v += red[((s - 1) * 4 + w) * 1024 + row * 64 + dblk * 16 + il];
                out[(size_t)(i0 + row) * OUT_COLS + w * DHEAD + dblk * 16 + il] =
                    v * inv + bias[w * DHEAD + dblk * 16 + il];
            }
        }
    }
}

extern "C" void kernel_launch(void* const* d_in, const int* in_sizes, int n_in,
                              void* d_out, int out_size, void* d_ws, size_t ws_size,
                              hipStream_t stream) {
    const float* features  = (const float*)d_in[0];
    const int*   adjacency = (const int*)d_in[1];
    const float* weights   = (const float*)d_in[2];
    const float* attention = (const float*)d_in[3];
    const float* bias      = (const float*)d_in[4];
    float* out = (float*)d_out;

    char* ws = (char*)d_ws;
    char*               hP    = ws;                                       // 2 MB
    unsigned long long* bitsT = (unsigned long long*)(ws + 2u*1024*1024); // 2 MB
    float*              s1T   = (float*)(ws + 4u*1024*1024);              // 64 KB
    float*              s2T   = (float*)(ws + 4u*1024*1024 + 64u*1024);   // 64 KB

    k_pack<<<dim3(2048), 256, 0, stream>>>(adjacency, bitsT);
    k_gemm_fused<<<dim3(128, 4), 256, 0, stream>>>(features, weights, attention,
                                                   hP, s1T, s2T);
    k_gat<<<dim3(256), 1024, 0, stream>>>(bitsT, hP, s1T, s2T, bias, out);
}